// Round 2
// baseline (904.814 us; speedup 1.0000x reference)
//
#include <hip/hip_runtime.h>

#define DEV __device__ __forceinline__

typedef float f32x4 __attribute__((ext_vector_type(4)));
typedef __bf16 bf16x8 __attribute__((ext_vector_type(8)));
#define MFMA16(a,b,c) __builtin_amdgcn_mfma_f32_16x16x32_bf16(a,b,c,0,0,0)

#define ASTRIDE 136   // bf16 A-buffer stride (272 B, 16B-aligned, 2-way max)
#define QSTRIDE 72    // bf16 K/V stride (144 B, 16B-aligned)
#define PSTRIDE 132   // fp32 prologue stride (16B-aligned rows, conflict-light)

DEV float wsum(float v){
  #pragma unroll
  for (int o = 32; o > 0; o >>= 1) v += __shfl_xor(v, o, 64);
  return v;
}

DEV float gelu_f(float x){
  float u = 0.7978845608028654f * (x + 0.044715f * x * x * x);
  float e = __expf(2.f * u);
  float th = 1.f - 2.f / (e + 1.f);
  return 0.5f * x * (1.f + th);
}

// ---------------- LN over rows of 128 (wave per row) ----------------
__global__ __launch_bounds__(256) void ln_kernel(const float* in,
    float* out0, float* out1,
    const float* __restrict__ g, const float* __restrict__ bb, int nrows)
{
  int w = threadIdx.x >> 6, l = threadIdx.x & 63;
  int row = blockIdx.x * 4 + w;
  if (row >= nrows) return;
  const float* rp = in + (size_t)row * 128;
  float v0 = rp[l], v1 = rp[l + 64];
  float m = wsum(v0 + v1) * 0.0078125f;
  float d0 = v0 - m, d1 = v1 - m;
  float var = wsum(d0 * d0 + d1 * d1) * 0.0078125f;
  float rs = rsqrtf(var + 1e-5f);
  float o0 = d0 * rs * g[l] + bb[l];
  float o1 = d1 * rs * g[l + 64] + bb[l + 64];
  size_t base = (size_t)row * 128;
  out0[base + l] = o0; out0[base + l + 64] = o1;
  if (out1){ out1[base + l] = o0; out1[base + l + 64] = o1; }
}

// ---------------- weight prep: fp32 [K][N] -> bf16 fragment-major ----------
// dst[((mat*tpm + nt*(K/32)+kt)*64 + lane)*8 + j] = W[kt*32+(lane>>4)*8+j][nt*16+(lane&15)]
__global__ __launch_bounds__(256) void prep_w(
    const float* __restrict__ Wa, const float* __restrict__ Wb,
    __bf16* __restrict__ dst, int K, int N, int nmat)
{
  int tid = blockIdx.x * 256 + threadIdx.x;
  int tpm = (N >> 4) * (K >> 5);
  if (tid >= nmat * tpm * 64) return;
  int lane = tid & 63;
  int tile = (tid >> 6) % tpm;
  int mat  = tid / (tpm * 64);
  const float* W;
  if (nmat == 1) W = Wa;
  else W = ((mat >> 1) ? Wb : Wa) + (size_t)(mat & 1) * K * N;
  int kdiv = K >> 5;
  int nt = tile / kdiv, kt = tile - nt * kdiv;
  int col  = nt * 16 + (lane & 15);
  int krow = kt * 32 + (lane >> 4) * 8;
  __bf16 v[8];
  #pragma unroll
  for (int j = 0; j < 8; j++) v[j] = (__bf16)W[(size_t)(krow + j) * N + col];
  *(bf16x8*)(dst + (size_t)tid * 8) = *(bf16x8*)v;
}

// ---------------- xmap = relu(X @ textW + b) via MFMA ----------------
__global__ __launch_bounds__(256) void xmap_mfma(
    const float* __restrict__ X, const __bf16* __restrict__ wt,
    const float* __restrict__ bias, float* __restrict__ out)
{
  __shared__ __bf16 xb[64 * ASTRIDE];
  const int t = threadIdx.x, w = t >> 6, l = t & 63, lm = l & 15, quad = l >> 4;
  const int r0 = blockIdx.x * 64;
  f32x4 acc[8];
  #pragma unroll
  for (int nt = 0; nt < 8; nt++) acc[nt] = (f32x4){0.f,0.f,0.f,0.f};
  for (int kc = 0; kc < 6; kc++){
    for (int i = t; i < 64 * 32; i += 256){
      int r = i >> 5, c4 = (i & 31) * 4;
      float4 v = make_float4(0.f,0.f,0.f,0.f);
      if (r0 + r < 50000) v = *(const float4*)&X[(size_t)(r0 + r) * 768 + kc * 128 + c4];
      xb[r*ASTRIDE + c4 + 0] = (__bf16)v.x;
      xb[r*ASTRIDE + c4 + 1] = (__bf16)v.y;
      xb[r*ASTRIDE + c4 + 2] = (__bf16)v.z;
      xb[r*ASTRIDE + c4 + 3] = (__bf16)v.w;
    }
    __syncthreads();
    bf16x8 af[4];
    #pragma unroll
    for (int kt = 0; kt < 4; kt++)
      af[kt] = *(const bf16x8*)&xb[(w*16 + lm)*ASTRIDE + kt*32 + quad*8];
    #pragma unroll
    for (int nt = 0; nt < 8; nt++)
      #pragma unroll
      for (int kt = 0; kt < 4; kt++)
        acc[nt] = MFMA16(af[kt], *(const bf16x8*)(wt + ((size_t)(nt*24 + kc*4 + kt)*64 + l)*8), acc[nt]);
    __syncthreads();
  }
  #pragma unroll
  for (int nt = 0; nt < 8; nt++){
    int n = nt*16 + lm;
    float bs = bias[n];
    #pragma unroll
    for (int r = 0; r < 4; r++){
      int row = r0 + w*16 + quad*4 + r;
      if (row < 50000) out[(size_t)row*128 + n] = fmaxf(acc[nt][r] + bs, 0.f);
    }
  }
}

// ---------------- encoder params ----------------
struct EncP {
  const float *pos, *ln0g, *ln0b, *bqkv, *bo, *ln1g, *ln1b, *b1, *b2, *ln2g, *ln2b;
  const __bf16 *wq, *wo, *w1, *w2;  // fragment-major bases (layer strides: 49152/16384/65536/65536)
  const float* emb;
  float* outT;
};

// LN over the wave's 16-row band held in registers (C layout: res[nt][r] =
// h[mb+quad*4+r][nt*16+lm]).  Row reduce = 8 local + 4 shfl over the 16-lane
// group.  No LDS, no barriers, fully parallel.
DEV void ln_reg(float res[8][4], const float* g, const float* bb, int lm){
  float gv[8], bv[8];
  #pragma unroll
  for (int nt = 0; nt < 8; nt++){ gv[nt] = g[nt*16 + lm]; bv[nt] = bb[nt*16 + lm]; }
  #pragma unroll
  for (int r = 0; r < 4; r++){
    float s = 0.f;
    #pragma unroll
    for (int nt = 0; nt < 8; nt++) s += res[nt][r];
    s += __shfl_xor(s, 1, 64); s += __shfl_xor(s, 2, 64);
    s += __shfl_xor(s, 4, 64); s += __shfl_xor(s, 8, 64);
    float mean = s * 0.0078125f;
    float v = 0.f;
    #pragma unroll
    for (int nt = 0; nt < 8; nt++){ float d = res[nt][r] - mean; v += d * d; }
    v += __shfl_xor(v, 1, 64); v += __shfl_xor(v, 2, 64);
    v += __shfl_xor(v, 4, 64); v += __shfl_xor(v, 8, 64);
    float rs = rsqrtf(v * 0.0078125f + 1e-5f);
    #pragma unroll
    for (int nt = 0; nt < 8; nt++)
      res[nt][r] = (res[nt][r] - mean) * rs * gv[nt] + bv[nt];
  }
}

// stage the wave's residual band to ab as bf16 (wave-private rows -> no barrier)
DEV void stage_res(const float res[8][4], __bf16* ab, int mb, int quad, int lm){
  #pragma unroll
  for (int r = 0; r < 4; r++){
    int m = mb + quad*4 + r;
    #pragma unroll
    for (int nt = 0; nt < 8; nt++)
      ab[m*ASTRIDE + nt*16 + lm] = (__bf16)res[nt][r];
  }
}

// ---------------- full encoder (MFMA), one block per sequence ----------------
// Residual stream lives in registers (32 f32/lane, MFMA C layout).  LDS pool:
// ab 17408 (h/Q/P/O/f1 staging, fully wave-private) + kb 9216 + vb 9216 =
// 35840 B -> 4 blocks/CU (was 72 KB -> 2).  Prologue overlays pool[0:26400]
// as fp32 [50][132] for the gather+LN0 coalesced pass.  Only barriers left
// guard the cross-wave K/V buffers (2 per head).
__global__ __launch_bounds__(256, 4) void encoder_mfma(
    EncP P0, EncP P1, const int* __restrict__ itemid, const float* __restrict__ mask)
{
  EncP P = (blockIdx.x < 256) ? P0 : P1;
  const int b = blockIdx.x & 255;
  const int t = threadIdx.x, w = t >> 6, l = t & 63;
  const int lm = l & 15, quad = l >> 4;
  const int mb = w * 16;        // this wave's M band
  const int am = mb + lm;       // A-fragment row for this lane

  __shared__ __align__(16) char pool[35840];
  __bf16* ab = (__bf16*)pool;                    // 64 x ASTRIDE
  __bf16* kb = (__bf16*)(pool + 17408);          // 64 x QSTRIDE  [ki][d]
  __bf16* vb = (__bf16*)(pool + 17408 + 9216);   // 64 x QSTRIDE  [d][ki]
  float*  hfp = (float*)pool;                    // prologue-only fp32 [50][PSTRIDE]
  __shared__ float maskv[64];

  if (t < 64) maskv[t] = (t < 50) ? mask[b*50 + t] : 0.f;

  // gather + pos + LN0 (wave-per-row, coalesced) -> fp32 pool
  for (int r = w; r < 50; r += 4){
    int it = itemid[b*50 + r];
    const float* er = P.emb + (size_t)it * 128;
    float v0 = er[l]      + P.pos[r*128 + l];
    float v1 = er[l + 64] + P.pos[r*128 + l + 64];
    float m = wsum(v0 + v1) * 0.0078125f;
    float d0 = v0 - m, d1 = v1 - m;
    float var = wsum(d0*d0 + d1*d1) * 0.0078125f;
    float rs = rsqrtf(var + 1e-5f);
    hfp[r*PSTRIDE + l]      = d0 * rs * P.ln0g[l] + P.ln0b[l];
    hfp[r*PSTRIDE + l + 64] = d1 * rs * P.ln0g[l + 64] + P.ln0b[l + 64];
  }
  __syncthreads();

  // pick up this lane's residual band into registers (C layout)
  float res[8][4];
  #pragma unroll
  for (int r = 0; r < 4; r++){
    int m = mb + quad*4 + r;
    #pragma unroll
    for (int nt = 0; nt < 8; nt++)
      res[nt][r] = (m < 50) ? hfp[m*PSTRIDE + nt*16 + lm] : 0.f;
  }
  __syncthreads();   // all hfp reads done before ab/kb (aliased) writes

  for (int lay = 0; lay < 2; ++lay){
    const __bf16* wq = P.wq + lay * 49152;
    const __bf16* wo = P.wo + lay * 16384;
    const __bf16* w1 = P.w1 + lay * 65536;
    const __bf16* w2 = P.w2 + lay * 65536;
    const float* bq  = P.bqkv + lay * 384;
    const float* bo  = P.bo   + lay * 128;
    const float* g1  = P.ln1g + lay * 128;
    const float* b1n = P.ln1b + lay * 128;
    const float* b1f = P.b1   + lay * 512;
    const float* b2f = P.b2   + lay * 128;
    const float* g2  = P.ln2g + lay * 128;
    const float* b2n = P.ln2b + lay * 128;

    // h -> ab (bf16, own band), then h A-fragments to regs for both heads
    stage_res(res, ab, mb, quad, lm);
    bf16x8 afh[4];
    #pragma unroll
    for (int kt = 0; kt < 4; kt++)
      afh[kt] = *(const bf16x8*)&ab[am*ASTRIDE + kt*32 + quad*8];

    for (int hd = 0; hd < 2; hd++){
      __syncthreads();   // prior readers of kb/vb are done before overwrite

      // QKV GEMM for this head; Q -> ab cols [64,128) (wave-private),
      // K -> kb, V -> vb (transposed)
      #pragma unroll
      for (int part = 0; part < 3; part++){
        #pragma unroll
        for (int tt = 0; tt < 4; tt++){
          int nt = part*8 + hd*4 + tt;
          f32x4 acc = (f32x4){0.f,0.f,0.f,0.f};
          #pragma unroll
          for (int kt = 0; kt < 4; kt++)
            acc = MFMA16(afh[kt], *(const bf16x8*)(wq + ((size_t)(nt*4 + kt)*64 + l)*8), acc);
          int n = nt*16 + lm;
          float bias = bq[n];
          int d = n & 63;
          #pragma unroll
          for (int r = 0; r < 4; r++){
            int m = mb + quad*4 + r;
            float v = acc[r] + bias;
            if (part == 0)      ab[m*ASTRIDE + 64 + d] = (__bf16)v;
            else if (part == 1) kb[m*QSTRIDE + d] = (__bf16)v;
            else                vb[d*QSTRIDE + m] = (__bf16)v;
          }
        }
      }
      __syncthreads();   // K/V visible to all waves

      // QK^T for own 16 q-rows
      bf16x8 aq0 = *(const bf16x8*)&ab[am*ASTRIDE + 64 + quad*8];
      bf16x8 aq1 = *(const bf16x8*)&ab[am*ASTRIDE + 96 + quad*8];
      f32x4 sf[4];
      #pragma unroll
      for (int nt = 0; nt < 4; nt++){
        f32x4 acc = (f32x4){0.f,0.f,0.f,0.f};
        acc = MFMA16(aq0, *(const bf16x8*)&kb[(nt*16 + lm)*QSTRIDE + quad*8], acc);
        acc = MFMA16(aq1, *(const bf16x8*)&kb[(nt*16 + lm)*QSTRIDE + 32 + quad*8], acc);
        sf[nt] = acc;
      }
      #pragma unroll
      for (int r = 0; r < 4; r++){
        int q = mb + quad*4 + r;
        float sv[4];
        float mx = -3e38f;
        #pragma unroll
        for (int nt = 0; nt < 4; nt++){
          int ki = nt*16 + lm;
          float s = sf[nt][r] * 0.125f;
          bool keep = (ki <= q) && (maskv[ki] != 0.f);
          s = keep ? s : -1e9f;
          sv[nt] = s; mx = fmaxf(mx, s);
        }
        #pragma unroll
        for (int o = 1; o < 16; o <<= 1) mx = fmaxf(mx, __shfl_xor(mx, o, 64));
        float sum = 0.f;
        #pragma unroll
        for (int nt = 0; nt < 4; nt++){ float p = __expf(sv[nt] - mx); sv[nt] = p; sum += p; }
        #pragma unroll
        for (int o = 1; o < 16; o <<= 1) sum += __shfl_xor(sum, o, 64);
        float inv = 1.f / sum;
        #pragma unroll
        for (int nt = 0; nt < 4; nt++)
          ab[q*ASTRIDE + 64 + nt*16 + lm] = (__bf16)(sv[nt] * inv);  // P over dead Q
      }
      // PV -> O into ab cols [hd*64, hd*64+64) (own band; ap consumed first)
      bf16x8 ap0 = *(const bf16x8*)&ab[am*ASTRIDE + 64 + quad*8];
      bf16x8 ap1 = *(const bf16x8*)&ab[am*ASTRIDE + 96 + quad*8];
      #pragma unroll
      for (int nt = 0; nt < 4; nt++){
        f32x4 acc = (f32x4){0.f,0.f,0.f,0.f};
        acc = MFMA16(ap0, *(const bf16x8*)&vb[(nt*16 + lm)*QSTRIDE + quad*8], acc);
        acc = MFMA16(ap1, *(const bf16x8*)&vb[(nt*16 + lm)*QSTRIDE + 32 + quad*8], acc);
        int dcol = hd*64 + nt*16 + lm;
        #pragma unroll
        for (int r = 0; r < 4; r++)
          ab[(mb + quad*4 + r)*ASTRIDE + dcol] = (__bf16)acc[r];
      }
    }

    // ---- res += O @ Wo + bo (C layouts match; no LDS for output) ----
    {
      bf16x8 af[4];
      #pragma unroll
      for (int kt = 0; kt < 4; kt++)
        af[kt] = *(const bf16x8*)&ab[am*ASTRIDE + kt*32 + quad*8];
      #pragma unroll
      for (int nt = 0; nt < 8; nt++){
        f32x4 acc = (f32x4){0.f,0.f,0.f,0.f};
        #pragma unroll
        for (int kt = 0; kt < 4; kt++)
          acc = MFMA16(af[kt], *(const bf16x8*)(wo + ((size_t)(nt*4 + kt)*64 + l)*8), acc);
        float bias = bo[nt*16 + lm];
        #pragma unroll
        for (int r = 0; r < 4; r++)
          res[nt][r] += acc[r] + bias;
      }
    }
    ln_reg(res, g1, b1n, lm);

    // ---- FFN fused over FF chunks of 128 (all wave-private staging) ----
    stage_res(res, ab, mb, quad, lm);
    {
      bf16x8 ah[4];
      #pragma unroll
      for (int kt = 0; kt < 4; kt++)
        ah[kt] = *(const bf16x8*)&ab[am*ASTRIDE + kt*32 + quad*8];
      f32x4 acc2[8];
      #pragma unroll
      for (int nt = 0; nt < 8; nt++) acc2[nt] = (f32x4){0.f,0.f,0.f,0.f};
      for (int ch = 0; ch < 4; ch++){
        #pragma unroll
        for (int nt = 0; nt < 8; nt++){
          f32x4 acc = (f32x4){0.f,0.f,0.f,0.f};
          #pragma unroll
          for (int kt = 0; kt < 4; kt++)
            acc = MFMA16(ah[kt], *(const bf16x8*)(w1 + ((size_t)((ch*8 + nt)*4 + kt)*64 + l)*8), acc);
          float bias = b1f[ch*128 + nt*16 + lm];
          #pragma unroll
          for (int r = 0; r < 4; r++)
            ab[(mb + quad*4 + r)*ASTRIDE + nt*16 + lm] = (__bf16)gelu_f(acc[r] + bias);
        }
        bf16x8 a2[4];
        #pragma unroll
        for (int kt = 0; kt < 4; kt++)
          a2[kt] = *(const bf16x8*)&ab[am*ASTRIDE + kt*32 + quad*8];
        #pragma unroll
        for (int nt = 0; nt < 8; nt++)
          #pragma unroll
          for (int kt = 0; kt < 4; kt++)
            acc2[nt] = MFMA16(a2[kt], *(const bf16x8*)(w2 + ((size_t)(nt*16 + ch*4 + kt)*64 + l)*8), acc2[nt]);
      }
      #pragma unroll
      for (int nt = 0; nt < 8; nt++){
        float bias = b2f[nt*16 + lm];
        #pragma unroll
        for (int r = 0; r < 4; r++)
          res[nt][r] += acc2[nt][r] + bias;
      }
    }
    ln_reg(res, g2, b2n, lm);
  }

  // last valid token -> transposed session emb [128][256], straight from regs
  {
    float sm = 0.f;
    for (int i = 0; i < 50; i++) sm += maskv[i];
    int idx = min(49, max(0, (int)sm - 1));
    #pragma unroll
    for (int r = 0; r < 4; r++){
      if (mb + quad*4 + r == idx){
        #pragma unroll
        for (int nt = 0; nt < 8; nt++)
          P.outT[(nt*16 + lm)*256 + b] = res[nt][r];
      }
    }
  }
}

// ---------------- scores: 16 items x 256 sessions per block ----------------
__global__ __launch_bounds__(256) void scores_kernel(
    const float* __restrict__ seT, const float* __restrict__ sfT,
    const float* __restrict__ ie,  const float* __restrict__ xm,
    float* __restrict__ sc, float* __restrict__ s1, float* __restrict__ s2)
{
  __shared__ float iet[16 * 128];
  __shared__ float xmt[16 * 128];
  const int t = threadIdx.x;
  const size_t j0 = (size_t)blockIdx.x * 16;
  {
    const float4* ig = (const float4*)(ie + j0 * 128);
    const float4* xg = (const float4*)(xm + j0 * 128);
    float4* a = (float4*)iet; float4* c4 = (float4*)xmt;
    for (int i = t; i < 512; i += 256){ a[i] = ig[i]; c4[i] = xg[i]; }
  }
  __syncthreads();
  float a1[16], a2[16];
  #pragma unroll
  for (int j = 0; j < 16; j++){ a1[j] = 0.f; a2[j] = 0.f; }
  for (int k = 0; k < 128; k += 4){
    float se0 = seT[(k+0)*256 + t], se1 = seT[(k+1)*256 + t];
    float se2 = seT[(k+2)*256 + t], se3 = seT[(k+3)*256 + t];
    float sf0 = sfT[(k+0)*256 + t], sf1 = sfT[(k+1)*256 + t];
    float sf2 = sfT[(k+2)*256 + t], sf3 = sfT[(k+3)*256 + t];
    #pragma unroll
    for (int j = 0; j < 16; j++){
      float4 iv = *(const float4*)&iet[j*128 + k];
      float4 xv = *(const float4*)&xmt[j*128 + k];
      a1[j] += iv.x*se0 + iv.y*se1 + iv.z*se2 + iv.w*se3;
      a2[j] += xv.x*sf0 + xv.y*sf1 + xv.z*sf2 + xv.w*sf3;
    }
  }
  size_t rb = (size_t)t * 50000 + j0;
  #pragma unroll
  for (int j = 0; j < 16; j += 4){
    float4 v1 = make_float4(a1[j], a1[j+1], a1[j+2], a1[j+3]);
    float4 v2 = make_float4(a2[j]*10.f, a2[j+1]*10.f, a2[j+2]*10.f, a2[j+3]*10.f);
    float4 vs = make_float4(0.5f*(v1.x+v2.x), 0.5f*(v1.y+v2.y),
                            0.5f*(v1.z+v2.z), 0.5f*(v1.w+v2.w));
    *(float4*)&s1[rb + j] = v1;
    *(float4*)&s2[rb + j] = v2;
    *(float4*)&sc[rb + j] = vs;
  }
}

// ---------------- launcher ----------------
extern "C" void kernel_launch(void* const* d_in, const int* in_sizes, int n_in,
                              void* d_out, int out_size, void* d_ws, size_t ws_size,
                              hipStream_t stream)
{
  const float* x       = (const float*)d_in[0];
  const int*   itemid  = (const int*)d_in[4];
  const float* mask    = (const float*)d_in[5];
  const float* id_emb  = (const float*)d_in[6];
  const float* id_g    = (const float*)d_in[7];
  const float* id_b    = (const float*)d_in[8];
  const float* text_W  = (const float*)d_in[9];
  const float* text_b  = (const float*)d_in[10];
  const float* text_g  = (const float*)d_in[11];
  const float* text_bb = (const float*)d_in[12];

  float* out = (float*)d_out;
  float* o_scores = out;                      // [256][50000]
  float* o_s1     = out + 12800000;
  float* o_s2     = out + 25600000;
  float* o_item   = out + 38400000;           // [50000][128]
  float* o_gnn    = out + 44800000;
  float* o_xmap   = out + 51200000;

  float* seT = (float*)d_ws;                  // [128][256]
  float* sfT = seT + 32768;
  __bf16* wp   = (__bf16*)((char*)d_ws + 262144);
  __bf16* wqkv = wp;                          // 4 mats x 49152
  __bf16* wo   = wp + 196608;                 // 4 x 16384
  __bf16* w1p  = wp + 262144;                 // 4 x 65536
  __bf16* w2p  = wp + 524288;                 // 4 x 65536
  __bf16* wtx  = wp + 786432;                 // 98304

  // weight prep (bf16, fragment-major); mat order = [enc][layer]
  prep_w<<<96, 256, 0, stream>>>((const float*)d_in[16], (const float*)d_in[31], wqkv, 128, 384, 4);
  prep_w<<<32, 256, 0, stream>>>((const float*)d_in[18], (const float*)d_in[33], wo,   128, 128, 4);
  prep_w<<<128,256, 0, stream>>>((const float*)d_in[22], (const float*)d_in[37], w1p,  128, 512, 4);
  prep_w<<<128,256, 0, stream>>>((const float*)d_in[24], (const float*)d_in[39], w2p,  512, 128, 4);
  prep_w<<<48, 256, 0, stream>>>(text_W, text_W, wtx, 768, 128, 1);

  ln_kernel<<<12500, 256, 0, stream>>>(id_emb, o_item, o_gnn, id_g, id_b, 50000);
  xmap_mfma<<<782, 256, 0, stream>>>(x, wtx, text_b, o_xmap);
  ln_kernel<<<12500, 256, 0, stream>>>(o_xmap, o_xmap, nullptr, text_g, text_bb, 50000);

  EncP P0, P1;
  P0.pos = (const float*)d_in[13]; P0.ln0g = (const float*)d_in[14]; P0.ln0b = (const float*)d_in[15];
  P0.bqkv = (const float*)d_in[17]; P0.bo = (const float*)d_in[19];
  P0.ln1g = (const float*)d_in[20]; P0.ln1b = (const float*)d_in[21];
  P0.b1 = (const float*)d_in[23]; P0.b2 = (const float*)d_in[25];
  P0.ln2g = (const float*)d_in[26]; P0.ln2b = (const float*)d_in[27];
  P0.wq = wqkv; P0.wo = wo; P0.w1 = w1p; P0.w2 = w2p;
  P0.emb = o_item; P0.outT = seT;

  P1.pos = (const float*)d_in[28]; P1.ln0g = (const float*)d_in[29]; P1.ln0b = (const float*)d_in[30];
  P1.bqkv = (const float*)d_in[32]; P1.bo = (const float*)d_in[34];
  P1.ln1g = (const float*)d_in[35]; P1.ln1b = (const float*)d_in[36];
  P1.b1 = (const float*)d_in[38]; P1.b2 = (const float*)d_in[40];
  P1.ln2g = (const float*)d_in[41]; P1.ln2b = (const float*)d_in[42];
  P1.wq = wqkv + 2*49152; P1.wo = wo + 2*16384; P1.w1 = w1p + 2*65536; P1.w2 = w2p + 2*65536;
  P1.emb = o_xmap; P1.outT = sfT;

  encoder_mfma<<<512, 256, 0, stream>>>(P0, P1, itemid, mask);

  scores_kernel<<<3125, 256, 0, stream>>>(seT, sfT, o_item, o_xmap,
                                          o_scores, o_s1, o_s2);
}

// Round 3
// 832.702 us; speedup vs baseline: 1.0866x; 1.0866x over previous
//
#include <hip/hip_runtime.h>

#define DEV __device__ __forceinline__

typedef float f32x4 __attribute__((ext_vector_type(4)));
typedef __bf16 bf16x8 __attribute__((ext_vector_type(8)));
#define MFMA16(a,b,c) __builtin_amdgcn_mfma_f32_16x16x32_bf16(a,b,c,0,0,0)

#define ASTRIDE 136   // bf16 A-buffer stride (272 B, 16B-aligned, 2-way max)
#define QSTRIDE 72    // bf16 K/V stride (144 B, 16B-aligned)
#define PSTRIDE 132   // fp32 prologue stride (16B-aligned rows, conflict-light)

DEV float wsum(float v){
  #pragma unroll
  for (int o = 32; o > 0; o >>= 1) v += __shfl_xor(v, o, 64);
  return v;
}

DEV float gelu_f(float x){
  float u = 0.7978845608028654f * (x + 0.044715f * x * x * x);
  float e = __expf(2.f * u);
  float th = 1.f - 2.f / (e + 1.f);
  return 0.5f * x * (1.f + th);
}

// ---------------- LN over rows of 128 (wave per row) ----------------
__global__ __launch_bounds__(256) void ln_kernel(const float* in,
    float* out0, float* out1,
    const float* __restrict__ g, const float* __restrict__ bb, int nrows)
{
  int w = threadIdx.x >> 6, l = threadIdx.x & 63;
  int row = blockIdx.x * 4 + w;
  if (row >= nrows) return;
  const float* rp = in + (size_t)row * 128;
  float v0 = rp[l], v1 = rp[l + 64];
  float m = wsum(v0 + v1) * 0.0078125f;
  float d0 = v0 - m, d1 = v1 - m;
  float var = wsum(d0 * d0 + d1 * d1) * 0.0078125f;
  float rs = rsqrtf(var + 1e-5f);
  float o0 = d0 * rs * g[l] + bb[l];
  float o1 = d1 * rs * g[l + 64] + bb[l + 64];
  size_t base = (size_t)row * 128;
  out0[base + l] = o0; out0[base + l + 64] = o1;
  if (out1){ out1[base + l] = o0; out1[base + l + 64] = o1; }
}

// ---------------- weight prep: fp32 [K][N] -> bf16 fragment-major ----------
// dst[((mat*tpm + nt*(K/32)+kt)*64 + lane)*8 + j] = W[kt*32+(lane>>4)*8+j][nt*16+(lane&15)]
__global__ __launch_bounds__(256) void prep_w(
    const float* __restrict__ Wa, const float* __restrict__ Wb,
    __bf16* __restrict__ dst, int K, int N, int nmat)
{
  int tid = blockIdx.x * 256 + threadIdx.x;
  int tpm = (N >> 4) * (K >> 5);
  if (tid >= nmat * tpm * 64) return;
  int lane = tid & 63;
  int tile = (tid >> 6) % tpm;
  int mat  = tid / (tpm * 64);
  const float* W;
  if (nmat == 1) W = Wa;
  else W = ((mat >> 1) ? Wb : Wa) + (size_t)(mat & 1) * K * N;
  int kdiv = K >> 5;
  int nt = tile / kdiv, kt = tile - nt * kdiv;
  int col  = nt * 16 + (lane & 15);
  int krow = kt * 32 + (lane >> 4) * 8;
  __bf16 v[8];
  #pragma unroll
  for (int j = 0; j < 8; j++) v[j] = (__bf16)W[(size_t)(krow + j) * N + col];
  *(bf16x8*)(dst + (size_t)tid * 8) = *(bf16x8*)v;
}

// ---------------- xmap = relu(X @ textW + b) via MFMA ----------------
__global__ __launch_bounds__(256) void xmap_mfma(
    const float* __restrict__ X, const __bf16* __restrict__ wt,
    const float* __restrict__ bias, float* __restrict__ out)
{
  __shared__ __bf16 xb[64 * ASTRIDE];
  const int t = threadIdx.x, w = t >> 6, l = t & 63, lm = l & 15, quad = l >> 4;
  const int r0 = blockIdx.x * 64;
  f32x4 acc[8];
  #pragma unroll
  for (int nt = 0; nt < 8; nt++) acc[nt] = (f32x4){0.f,0.f,0.f,0.f};
  for (int kc = 0; kc < 6; kc++){
    for (int i = t; i < 64 * 32; i += 256){
      int r = i >> 5, c4 = (i & 31) * 4;
      float4 v = make_float4(0.f,0.f,0.f,0.f);
      if (r0 + r < 50000) v = *(const float4*)&X[(size_t)(r0 + r) * 768 + kc * 128 + c4];
      xb[r*ASTRIDE + c4 + 0] = (__bf16)v.x;
      xb[r*ASTRIDE + c4 + 1] = (__bf16)v.y;
      xb[r*ASTRIDE + c4 + 2] = (__bf16)v.z;
      xb[r*ASTRIDE + c4 + 3] = (__bf16)v.w;
    }
    __syncthreads();
    bf16x8 af[4];
    #pragma unroll
    for (int kt = 0; kt < 4; kt++)
      af[kt] = *(const bf16x8*)&xb[(w*16 + lm)*ASTRIDE + kt*32 + quad*8];
    #pragma unroll
    for (int nt = 0; nt < 8; nt++)
      #pragma unroll
      for (int kt = 0; kt < 4; kt++)
        acc[nt] = MFMA16(af[kt], *(const bf16x8*)(wt + ((size_t)(nt*24 + kc*4 + kt)*64 + l)*8), acc[nt]);
    __syncthreads();
  }
  #pragma unroll
  for (int nt = 0; nt < 8; nt++){
    int n = nt*16 + lm;
    float bs = bias[n];
    #pragma unroll
    for (int r = 0; r < 4; r++){
      int row = r0 + w*16 + quad*4 + r;
      if (row < 50000) out[(size_t)row*128 + n] = fmaxf(acc[nt][r] + bs, 0.f);
    }
  }
}

// ---------------- encoder params ----------------
struct EncP {
  const float *pos, *ln0g, *ln0b, *bqkv, *bo, *ln1g, *ln1b, *b1, *b2, *ln2g, *ln2b;
  const __bf16 *wq, *wo, *w1, *w2;  // fragment-major bases (layer strides: 49152/16384/65536/65536)
  const float* emb;
  float* outT;
};

// LN over the wave's 16-row band held in registers (C layout: res[nt][r] =
// h[mb+quad*4+r][nt*16+lm]).  Row reduce = 8 local + 4 shfl over the 16-lane
// group.  No LDS, no barriers, fully parallel.
DEV void ln_reg(float res[8][4], const float* g, const float* bb, int lm){
  float gv[8], bv[8];
  #pragma unroll
  for (int nt = 0; nt < 8; nt++){ gv[nt] = g[nt*16 + lm]; bv[nt] = bb[nt*16 + lm]; }
  #pragma unroll
  for (int r = 0; r < 4; r++){
    float s = 0.f;
    #pragma unroll
    for (int nt = 0; nt < 8; nt++) s += res[nt][r];
    s += __shfl_xor(s, 1, 64); s += __shfl_xor(s, 2, 64);
    s += __shfl_xor(s, 4, 64); s += __shfl_xor(s, 8, 64);
    float mean = s * 0.0078125f;
    float v = 0.f;
    #pragma unroll
    for (int nt = 0; nt < 8; nt++){ float d = res[nt][r] - mean; v += d * d; }
    v += __shfl_xor(v, 1, 64); v += __shfl_xor(v, 2, 64);
    v += __shfl_xor(v, 4, 64); v += __shfl_xor(v, 8, 64);
    float rs = rsqrtf(v * 0.0078125f + 1e-5f);
    #pragma unroll
    for (int nt = 0; nt < 8; nt++)
      res[nt][r] = (res[nt][r] - mean) * rs * gv[nt] + bv[nt];
  }
}

// stage the wave's residual band to ab as bf16 (wave-private rows -> no barrier)
DEV void stage_res(const float res[8][4], __bf16* ab, int mb, int quad, int lm){
  #pragma unroll
  for (int r = 0; r < 4; r++){
    int m = mb + quad*4 + r;
    #pragma unroll
    for (int nt = 0; nt < 8; nt++)
      ab[m*ASTRIDE + nt*16 + lm] = (__bf16)res[nt][r];
  }
}

// ---------------- full encoder (MFMA), one block per sequence ----------------
// Residual stream in registers (32 f32/lane, MFMA C layout).  Grid = 512
// blocks on 256 CUs caps occupancy at 2 blocks/CU, so LDS budget is 80 KB;
// hold BOTH heads' Q/K/V -> one 24-tile QKV pass and only 2 barriers/layer.
// Pool: ab 17408 + qbuf 18432 + kb 18432 + vb 18432 = 72704 B.
// launch_bounds(256,2): VGPR cap 256 (grid caps us at 2 waves/SIMD anyway)
// -> no spill (round-2 lesson: (256,4) forced 64 VGPRs + 21 MB scratch).
__global__ __launch_bounds__(256, 2) void encoder_mfma(
    EncP P0, EncP P1, const int* __restrict__ itemid, const float* __restrict__ mask)
{
  EncP P = (blockIdx.x < 256) ? P0 : P1;
  const int b = blockIdx.x & 255;
  const int t = threadIdx.x, w = t >> 6, l = t & 63;
  const int lm = l & 15, quad = l >> 4;
  const int mb = w * 16;        // this wave's M band
  const int am = mb + lm;       // A-fragment row for this lane

  __shared__ __align__(16) char pool[72704];
  __bf16* ab   = (__bf16*)pool;                    // 64 x ASTRIDE (h/O/f1 staging)
  __bf16* qbuf = (__bf16*)(pool + 17408);          // 2 x 64 x QSTRIDE  Q (-> P)
  __bf16* kb   = (__bf16*)(pool + 35840);          // 2 x 64 x QSTRIDE  K [ki][d]
  __bf16* vb   = (__bf16*)(pool + 54272);          // 2 x 64 x QSTRIDE  V [d][ki]
  float*  hfp  = (float*)pool;                     // prologue fp32 [50][PSTRIDE]
  __shared__ float maskv[64];

  if (t < 64) maskv[t] = (t < 50) ? mask[b*50 + t] : 0.f;

  // gather + pos + LN0 (wave-per-row, coalesced) -> fp32 pool
  for (int r = w; r < 50; r += 4){
    int it = itemid[b*50 + r];
    const float* er = P.emb + (size_t)it * 128;
    float v0 = er[l]      + P.pos[r*128 + l];
    float v1 = er[l + 64] + P.pos[r*128 + l + 64];
    float m = wsum(v0 + v1) * 0.0078125f;
    float d0 = v0 - m, d1 = v1 - m;
    float var = wsum(d0*d0 + d1*d1) * 0.0078125f;
    float rs = rsqrtf(var + 1e-5f);
    hfp[r*PSTRIDE + l]      = d0 * rs * P.ln0g[l] + P.ln0b[l];
    hfp[r*PSTRIDE + l + 64] = d1 * rs * P.ln0g[l + 64] + P.ln0b[l + 64];
  }
  __syncthreads();

  // pick up this lane's residual band into registers (C layout)
  float res[8][4];
  #pragma unroll
  for (int r = 0; r < 4; r++){
    int m = mb + quad*4 + r;
    #pragma unroll
    for (int nt = 0; nt < 8; nt++)
      res[nt][r] = (m < 50) ? hfp[m*PSTRIDE + nt*16 + lm] : 0.f;
  }

  for (int lay = 0; lay < 2; ++lay){
    const __bf16* wq = P.wq + lay * 49152;
    const __bf16* wo = P.wo + lay * 16384;
    const __bf16* w1 = P.w1 + lay * 65536;
    const __bf16* w2 = P.w2 + lay * 65536;
    const float* bq  = P.bqkv + lay * 384;
    const float* bo  = P.bo   + lay * 128;
    const float* g1  = P.ln1g + lay * 128;
    const float* b1n = P.ln1b + lay * 128;
    const float* b1f = P.b1   + lay * 512;
    const float* b2f = P.b2   + lay * 128;
    const float* g2  = P.ln2g + lay * 128;
    const float* b2n = P.ln2b + lay * 128;

    // layer-top barrier: lay0 -> all hfp reads done before aliased writes;
    // lay1 -> all readers of kb/vb/qbuf finished before overwrite.
    __syncthreads();

    // h -> ab (bf16, own band), A-fragments to regs
    stage_res(res, ab, mb, quad, lm);
    bf16x8 afh[4];
    #pragma unroll
    for (int kt = 0; kt < 4; kt++)
      afh[kt] = *(const bf16x8*)&ab[am*ASTRIDE + kt*32 + quad*8];

    // ---- QKV GEMM, both heads in one pass: 24 N-tiles of [64x128]@[128x384]
    #pragma unroll
    for (int nt = 0; nt < 24; nt++){
      f32x4 acc = (f32x4){0.f,0.f,0.f,0.f};
      #pragma unroll
      for (int kt = 0; kt < 4; kt++)
        acc = MFMA16(afh[kt], *(const bf16x8*)(wq + ((size_t)(nt*4 + kt)*64 + l)*8), acc);
      int n = nt*16 + lm;
      float bias = bq[n];
      int part = n >> 7, hd = (n >> 6) & 1, d = n & 63;
      __bf16* q_ = qbuf + hd*64*QSTRIDE;
      __bf16* k_ = kb   + hd*64*QSTRIDE;
      __bf16* v_ = vb   + hd*64*QSTRIDE;
      #pragma unroll
      for (int r = 0; r < 4; r++){
        int m = mb + quad*4 + r;
        float v = acc[r] + bias;
        if (part == 0)      q_[m*QSTRIDE + d] = (__bf16)v;   // own band
        else if (part == 1) k_[m*QSTRIDE + d] = (__bf16)v;
        else                v_[d*QSTRIDE + m] = (__bf16)v;   // transposed
      }
    }
    __syncthreads();   // K/V visible to all waves

    // ---- attention, both heads, zero barriers (all wave-private) ----
    #pragma unroll
    for (int hd = 0; hd < 2; hd++){
      __bf16* q_ = qbuf + hd*64*QSTRIDE;   // Q, then P over dead Q
      const __bf16* k_ = kb + hd*64*QSTRIDE;
      const __bf16* v_ = vb + hd*64*QSTRIDE;
      bf16x8 aq0 = *(const bf16x8*)&q_[am*QSTRIDE + quad*8];
      bf16x8 aq1 = *(const bf16x8*)&q_[am*QSTRIDE + 32 + quad*8];
      f32x4 sf[4];
      #pragma unroll
      for (int nt = 0; nt < 4; nt++){
        f32x4 acc = (f32x4){0.f,0.f,0.f,0.f};
        acc = MFMA16(aq0, *(const bf16x8*)&k_[(nt*16 + lm)*QSTRIDE + quad*8], acc);
        acc = MFMA16(aq1, *(const bf16x8*)&k_[(nt*16 + lm)*QSTRIDE + 32 + quad*8], acc);
        sf[nt] = acc;
      }
      #pragma unroll
      for (int r = 0; r < 4; r++){
        int q = mb + quad*4 + r;
        float sv[4];
        float mx = -3e38f;
        #pragma unroll
        for (int nt = 0; nt < 4; nt++){
          int ki = nt*16 + lm;
          float s = sf[nt][r] * 0.125f;
          bool keep = (ki <= q) && (maskv[ki] != 0.f);
          s = keep ? s : -1e9f;
          sv[nt] = s; mx = fmaxf(mx, s);
        }
        #pragma unroll
        for (int o = 1; o < 16; o <<= 1) mx = fmaxf(mx, __shfl_xor(mx, o, 64));
        float sum = 0.f;
        #pragma unroll
        for (int nt = 0; nt < 4; nt++){ float p = __expf(sv[nt] - mx); sv[nt] = p; sum += p; }
        #pragma unroll
        for (int o = 1; o < 16; o <<= 1) sum += __shfl_xor(sum, o, 64);
        float inv = 1.f / sum;
        #pragma unroll
        for (int nt = 0; nt < 4; nt++)
          q_[q*QSTRIDE + nt*16 + lm] = (__bf16)(sv[nt] * inv);  // P over dead Q
      }
      // PV -> O into ab cols [hd*64, hd*64+64) (own band)
      bf16x8 ap0 = *(const bf16x8*)&q_[am*QSTRIDE + quad*8];
      bf16x8 ap1 = *(const bf16x8*)&q_[am*QSTRIDE + 32 + quad*8];
      #pragma unroll
      for (int nt = 0; nt < 4; nt++){
        f32x4 acc = (f32x4){0.f,0.f,0.f,0.f};
        acc = MFMA16(ap0, *(const bf16x8*)&v_[(nt*16 + lm)*QSTRIDE + quad*8], acc);
        acc = MFMA16(ap1, *(const bf16x8*)&v_[(nt*16 + lm)*QSTRIDE + 32 + quad*8], acc);
        int dcol = hd*64 + nt*16 + lm;
        #pragma unroll
        for (int r = 0; r < 4; r++)
          ab[(mb + quad*4 + r)*ASTRIDE + dcol] = (__bf16)acc[r];
      }
    }

    // ---- res += O @ Wo + bo (C layouts match) ----
    {
      bf16x8 af[4];
      #pragma unroll
      for (int kt = 0; kt < 4; kt++)
        af[kt] = *(const bf16x8*)&ab[am*ASTRIDE + kt*32 + quad*8];
      #pragma unroll
      for (int nt = 0; nt < 8; nt++){
        f32x4 acc = (f32x4){0.f,0.f,0.f,0.f};
        #pragma unroll
        for (int kt = 0; kt < 4; kt++)
          acc = MFMA16(af[kt], *(const bf16x8*)(wo + ((size_t)(nt*4 + kt)*64 + l)*8), acc);
        float bias = bo[nt*16 + lm];
        #pragma unroll
        for (int r = 0; r < 4; r++)
          res[nt][r] += acc[r] + bias;
      }
    }
    ln_reg(res, g1, b1n, lm);

    // ---- FFN fused over FF chunks of 128 (ab staging, wave-private) ----
    stage_res(res, ab, mb, quad, lm);
    {
      bf16x8 ah[4];
      #pragma unroll
      for (int kt = 0; kt < 4; kt++)
        ah[kt] = *(const bf16x8*)&ab[am*ASTRIDE + kt*32 + quad*8];
      f32x4 acc2[8];
      #pragma unroll
      for (int nt = 0; nt < 8; nt++) acc2[nt] = (f32x4){0.f,0.f,0.f,0.f};
      for (int ch = 0; ch < 4; ch++){
        #pragma unroll
        for (int nt = 0; nt < 8; nt++){
          f32x4 acc = (f32x4){0.f,0.f,0.f,0.f};
          #pragma unroll
          for (int kt = 0; kt < 4; kt++)
            acc = MFMA16(ah[kt], *(const bf16x8*)(w1 + ((size_t)((ch*8 + nt)*4 + kt)*64 + l)*8), acc);
          float bias = b1f[ch*128 + nt*16 + lm];
          #pragma unroll
          for (int r = 0; r < 4; r++)
            ab[(mb + quad*4 + r)*ASTRIDE + nt*16 + lm] = (__bf16)gelu_f(acc[r] + bias);
        }
        bf16x8 a2[4];
        #pragma unroll
        for (int kt = 0; kt < 4; kt++)
          a2[kt] = *(const bf16x8*)&ab[am*ASTRIDE + kt*32 + quad*8];
        #pragma unroll
        for (int nt = 0; nt < 8; nt++)
          #pragma unroll
          for (int kt = 0; kt < 4; kt++)
            acc2[nt] = MFMA16(a2[kt], *(const bf16x8*)(w2 + ((size_t)(nt*16 + ch*4 + kt)*64 + l)*8), acc2[nt]);
      }
      #pragma unroll
      for (int nt = 0; nt < 8; nt++){
        float bias = b2f[nt*16 + lm];
        #pragma unroll
        for (int r = 0; r < 4; r++)
          res[nt][r] += acc2[nt][r] + bias;
      }
    }
    ln_reg(res, g2, b2n, lm);
  }

  // last valid token -> transposed session emb [128][256], straight from regs
  {
    float sm = 0.f;
    for (int i = 0; i < 50; i++) sm += maskv[i];
    int idx = min(49, max(0, (int)sm - 1));
    #pragma unroll
    for (int r = 0; r < 4; r++){
      if (mb + quad*4 + r == idx){
        #pragma unroll
        for (int nt = 0; nt < 8; nt++)
          P.outT[(nt*16 + lm)*256 + b] = res[nt][r];
      }
    }
  }
}

// ---------------- scores: 16 items x 256 sessions per block ----------------
__global__ __launch_bounds__(256) void scores_kernel(
    const float* __restrict__ seT, const float* __restrict__ sfT,
    const float* __restrict__ ie,  const float* __restrict__ xm,
    float* __restrict__ sc, float* __restrict__ s1, float* __restrict__ s2)
{
  __shared__ float iet[16 * 128];
  __shared__ float xmt[16 * 128];
  const int t = threadIdx.x;
  const size_t j0 = (size_t)blockIdx.x * 16;
  {
    const float4* ig = (const float4*)(ie + j0 * 128);
    const float4* xg = (const float4*)(xm + j0 * 128);
    float4* a = (float4*)iet; float4* c4 = (float4*)xmt;
    for (int i = t; i < 512; i += 256){ a[i] = ig[i]; c4[i] = xg[i]; }
  }
  __syncthreads();
  float a1[16], a2[16];
  #pragma unroll
  for (int j = 0; j < 16; j++){ a1[j] = 0.f; a2[j] = 0.f; }
  for (int k = 0; k < 128; k += 4){
    float se0 = seT[(k+0)*256 + t], se1 = seT[(k+1)*256 + t];
    float se2 = seT[(k+2)*256 + t], se3 = seT[(k+3)*256 + t];
    float sf0 = sfT[(k+0)*256 + t], sf1 = sfT[(k+1)*256 + t];
    float sf2 = sfT[(k+2)*256 + t], sf3 = sfT[(k+3)*256 + t];
    #pragma unroll
    for (int j = 0; j < 16; j++){
      float4 iv = *(const float4*)&iet[j*128 + k];
      float4 xv = *(const float4*)&xmt[j*128 + k];
      a1[j] += iv.x*se0 + iv.y*se1 + iv.z*se2 + iv.w*se3;
      a2[j] += xv.x*sf0 + xv.y*sf1 + xv.z*sf2 + xv.w*sf3;
    }
  }
  size_t rb = (size_t)t * 50000 + j0;
  #pragma unroll
  for (int j = 0; j < 16; j += 4){
    float4 v1 = make_float4(a1[j], a1[j+1], a1[j+2], a1[j+3]);
    float4 v2 = make_float4(a2[j]*10.f, a2[j+1]*10.f, a2[j+2]*10.f, a2[j+3]*10.f);
    float4 vs = make_float4(0.5f*(v1.x+v2.x), 0.5f*(v1.y+v2.y),
                            0.5f*(v1.z+v2.z), 0.5f*(v1.w+v2.w));
    *(float4*)&s1[rb + j] = v1;
    *(float4*)&s2[rb + j] = v2;
    *(float4*)&sc[rb + j] = vs;
  }
}

// ---------------- launcher ----------------
extern "C" void kernel_launch(void* const* d_in, const int* in_sizes, int n_in,
                              void* d_out, int out_size, void* d_ws, size_t ws_size,
                              hipStream_t stream)
{
  const float* x       = (const float*)d_in[0];
  const int*   itemid  = (const int*)d_in[4];
  const float* mask    = (const float*)d_in[5];
  const float* id_emb  = (const float*)d_in[6];
  const float* id_g    = (const float*)d_in[7];
  const float* id_b    = (const float*)d_in[8];
  const float* text_W  = (const float*)d_in[9];
  const float* text_b  = (const float*)d_in[10];
  const float* text_g  = (const float*)d_in[11];
  const float* text_bb = (const float*)d_in[12];

  float* out = (float*)d_out;
  float* o_scores = out;                      // [256][50000]
  float* o_s1     = out + 12800000;
  float* o_s2     = out + 25600000;
  float* o_item   = out + 38400000;           // [50000][128]
  float* o_gnn    = out + 44800000;
  float* o_xmap   = out + 51200000;

  float* seT = (float*)d_ws;                  // [128][256]
  float* sfT = seT + 32768;
  __bf16* wp   = (__bf16*)((char*)d_ws + 262144);
  __bf16* wqkv = wp;                          // 4 mats x 49152
  __bf16* wo   = wp + 196608;                 // 4 x 16384
  __bf16* w1p  = wp + 262144;                 // 4 x 65536
  __bf16* w2p  = wp + 524288;                 // 4 x 65536
  __bf16* wtx  = wp + 786432;                 // 98304

  // weight prep (bf16, fragment-major); mat order = [enc][layer]
  prep_w<<<96, 256, 0, stream>>>((const float*)d_in[16], (const float*)d_in[31], wqkv, 128, 384, 4);
  prep_w<<<32, 256, 0, stream>>>((const float*)d_in[18], (const float*)d_in[33], wo,   128, 128, 4);
  prep_w<<<128,256, 0, stream>>>((const float*)d_in[22], (const float*)d_in[37], w1p,  128, 512, 4);
  prep_w<<<128,256, 0, stream>>>((const float*)d_in[24], (const float*)d_in[39], w2p,  512, 128, 4);
  prep_w<<<48, 256, 0, stream>>>(text_W, text_W, wtx, 768, 128, 1);

  ln_kernel<<<12500, 256, 0, stream>>>(id_emb, o_item, o_gnn, id_g, id_b, 50000);
  xmap_mfma<<<782, 256, 0, stream>>>(x, wtx, text_b, o_xmap);
  ln_kernel<<<12500, 256, 0, stream>>>(o_xmap, o_xmap, nullptr, text_g, text_bb, 50000);

  EncP P0, P1;
  P0.pos = (const float*)d_in[13]; P0.ln0g = (const float*)d_in[14]; P0.ln0b = (const float*)d_in[15];
  P0.bqkv = (const float*)d_in[17]; P0.bo = (const float*)d_in[19];
  P0.ln1g = (const float*)d_in[20]; P0.ln1b = (const float*)d_in[21];
  P0.b1 = (const float*)d_in[23]; P0.b2 = (const float*)d_in[25];
  P0.ln2g = (const float*)d_in[26]; P0.ln2b = (const float*)d_in[27];
  P0.wq = wqkv; P0.wo = wo; P0.w1 = w1p; P0.w2 = w2p;
  P0.emb = o_item; P0.outT = seT;

  P1.pos = (const float*)d_in[28]; P1.ln0g = (const float*)d_in[29]; P1.ln0b = (const float*)d_in[30];
  P1.bqkv = (const float*)d_in[32]; P1.bo = (const float*)d_in[34];
  P1.ln1g = (const float*)d_in[35]; P1.ln1b = (const float*)d_in[36];
  P1.b1 = (const float*)d_in[38]; P1.b2 = (const float*)d_in[40];
  P1.ln2g = (const float*)d_in[41]; P1.ln2b = (const float*)d_in[42];
  P1.wq = wqkv + 2*49152; P1.wo = wo + 2*16384; P1.w1 = w1p + 2*65536; P1.w2 = w2p + 2*65536;
  P1.emb = o_xmap; P1.outT = sfT;

  encoder_mfma<<<512, 256, 0, stream>>>(P0, P1, itemid, mask);

  scores_kernel<<<3125, 256, 0, stream>>>(seT, sfT, o_item, o_xmap,
                                          o_scores, o_s1, o_s2);
}

// Round 4
// 825.815 us; speedup vs baseline: 1.0957x; 1.0083x over previous
//
#include <hip/hip_runtime.h>

#define DEV __device__ __forceinline__

typedef float f32x4 __attribute__((ext_vector_type(4)));
typedef __bf16 bf16x8 __attribute__((ext_vector_type(8)));
#define MFMA16(a,b,c) __builtin_amdgcn_mfma_f32_16x16x32_bf16(a,b,c,0,0,0)

#define ASTRIDE 136   // bf16 A-buffer stride (272 B, 16B-aligned, 2-way max)
#define QSTRIDE 72    // bf16 K/V stride (144 B, 16B-aligned)
#define PSTRIDE 132   // fp32 prologue stride (16B-aligned rows, conflict-light)
#define CSTRIDE 132   // fp32 C-stage stride for scores epilogue

DEV float wsum(float v){
  #pragma unroll
  for (int o = 32; o > 0; o >>= 1) v += __shfl_xor(v, o, 64);
  return v;
}

DEV float gelu_f(float x){
  float u = 0.7978845608028654f * (x + 0.044715f * x * x * x);
  float e = __expf(2.f * u);
  float th = 1.f - 2.f / (e + 1.f);
  return 0.5f * x * (1.f + th);
}

// ---------------- LN over rows of 128 (wave per row) ----------------
__global__ __launch_bounds__(256) void ln_kernel(const float* in,
    float* out0, float* out1,
    const float* __restrict__ g, const float* __restrict__ bb, int nrows)
{
  int w = threadIdx.x >> 6, l = threadIdx.x & 63;
  int row = blockIdx.x * 4 + w;
  if (row >= nrows) return;
  const float* rp = in + (size_t)row * 128;
  float v0 = rp[l], v1 = rp[l + 64];
  float m = wsum(v0 + v1) * 0.0078125f;
  float d0 = v0 - m, d1 = v1 - m;
  float var = wsum(d0 * d0 + d1 * d1) * 0.0078125f;
  float rs = rsqrtf(var + 1e-5f);
  float o0 = d0 * rs * g[l] + bb[l];
  float o1 = d1 * rs * g[l + 64] + bb[l + 64];
  size_t base = (size_t)row * 128;
  out0[base + l] = o0; out0[base + l + 64] = o1;
  if (out1){ out1[base + l] = o0; out1[base + l + 64] = o1; }
}

// ---------------- weight prep: fp32 [K][N] -> bf16 fragment-major ----------
// dst[((mat*tpm + nt*(K/32)+kt)*64 + lane)*8 + j] = W[kt*32+(lane>>4)*8+j][nt*16+(lane&15)]
__global__ __launch_bounds__(256) void prep_w(
    const float* __restrict__ Wa, const float* __restrict__ Wb,
    __bf16* __restrict__ dst, int K, int N, int nmat)
{
  int tid = blockIdx.x * 256 + threadIdx.x;
  int tpm = (N >> 4) * (K >> 5);
  if (tid >= nmat * tpm * 64) return;
  int lane = tid & 63;
  int tile = (tid >> 6) % tpm;
  int mat  = tid / (tpm * 64);
  const float* W;
  if (nmat == 1) W = Wa;
  else W = ((mat >> 1) ? Wb : Wa) + (size_t)(mat & 1) * K * N;
  int kdiv = K >> 5;
  int nt = tile / kdiv, kt = tile - nt * kdiv;
  int col  = nt * 16 + (lane & 15);
  int krow = kt * 32 + (lane >> 4) * 8;
  __bf16 v[8];
  #pragma unroll
  for (int j = 0; j < 8; j++) v[j] = (__bf16)W[(size_t)(krow + j) * N + col];
  *(bf16x8*)(dst + (size_t)tid * 8) = *(bf16x8*)v;
}

// ---------------- item prep: fp32 row-major [50000][128] -> bf16 frag-major
// dst[((nt*4+kt)*64+lane)*8+j] = src[(nt*16+(lane&15))*128 + kt*32+(lane>>4)*8+j]
// (i.e. B[k][n] with B = items^T, matching prep_w's fragment layout)
__global__ __launch_bounds__(256) void prep_items(
    const float* __restrict__ src, __bf16* __restrict__ dst)
{
  int tid = blockIdx.x * 256 + threadIdx.x;     // 3125 blocks * 256 = 800000
  int lane = tid & 63, kt = (tid >> 6) & 3, nt = tid >> 8;
  if (nt >= 3125) return;
  const float* p = src + (size_t)(nt*16 + (lane & 15))*128 + kt*32 + (lane >> 4)*8;
  float4 v0 = *(const float4*)p, v1 = *(const float4*)(p + 4);
  __bf16 v[8] = {(__bf16)v0.x,(__bf16)v0.y,(__bf16)v0.z,(__bf16)v0.w,
                 (__bf16)v1.x,(__bf16)v1.y,(__bf16)v1.z,(__bf16)v1.w};
  *(bf16x8*)(dst + (size_t)tid * 8) = *(bf16x8*)v;
}

// ---------------- xmap = relu(X @ textW + b) via MFMA ----------------
__global__ __launch_bounds__(256) void xmap_mfma(
    const float* __restrict__ X, const __bf16* __restrict__ wt,
    const float* __restrict__ bias, float* __restrict__ out)
{
  __shared__ __bf16 xb[64 * ASTRIDE];
  const int t = threadIdx.x, w = t >> 6, l = t & 63, lm = l & 15, quad = l >> 4;
  const int r0 = blockIdx.x * 64;
  f32x4 acc[8];
  #pragma unroll
  for (int nt = 0; nt < 8; nt++) acc[nt] = (f32x4){0.f,0.f,0.f,0.f};
  for (int kc = 0; kc < 6; kc++){
    for (int i = t; i < 64 * 32; i += 256){
      int r = i >> 5, c4 = (i & 31) * 4;
      float4 v = make_float4(0.f,0.f,0.f,0.f);
      if (r0 + r < 50000) v = *(const float4*)&X[(size_t)(r0 + r) * 768 + kc * 128 + c4];
      xb[r*ASTRIDE + c4 + 0] = (__bf16)v.x;
      xb[r*ASTRIDE + c4 + 1] = (__bf16)v.y;
      xb[r*ASTRIDE + c4 + 2] = (__bf16)v.z;
      xb[r*ASTRIDE + c4 + 3] = (__bf16)v.w;
    }
    __syncthreads();
    bf16x8 af[4];
    #pragma unroll
    for (int kt = 0; kt < 4; kt++)
      af[kt] = *(const bf16x8*)&xb[(w*16 + lm)*ASTRIDE + kt*32 + quad*8];
    #pragma unroll
    for (int nt = 0; nt < 8; nt++)
      #pragma unroll
      for (int kt = 0; kt < 4; kt++)
        acc[nt] = MFMA16(af[kt], *(const bf16x8*)(wt + ((size_t)(nt*24 + kc*4 + kt)*64 + l)*8), acc[nt]);
    __syncthreads();
  }
  #pragma unroll
  for (int nt = 0; nt < 8; nt++){
    int n = nt*16 + lm;
    float bs = bias[n];
    #pragma unroll
    for (int r = 0; r < 4; r++){
      int row = r0 + w*16 + quad*4 + r;
      if (row < 50000) out[(size_t)row*128 + n] = fmaxf(acc[nt][r] + bs, 0.f);
    }
  }
}

// ---------------- encoder params ----------------
struct EncP {
  const float *pos, *ln0g, *ln0b, *bqkv, *bo, *ln1g, *ln1b, *b1, *b2, *ln2g, *ln2b;
  const __bf16 *wq, *wo, *w1, *w2;  // fragment-major bases (layer strides: 49152/16384/65536/65536)
  const float* emb;
  float* outT;
};

// LN over the wave's 16-row band held in registers (C layout: res[nt][r] =
// h[mb+quad*4+r][nt*16+lm]).  Row reduce = 8 local + 4 shfl over the 16-lane
// group.  No LDS, no barriers, fully parallel.
DEV void ln_reg(float res[8][4], const float* g, const float* bb, int lm){
  float gv[8], bv[8];
  #pragma unroll
  for (int nt = 0; nt < 8; nt++){ gv[nt] = g[nt*16 + lm]; bv[nt] = bb[nt*16 + lm]; }
  #pragma unroll
  for (int r = 0; r < 4; r++){
    float s = 0.f;
    #pragma unroll
    for (int nt = 0; nt < 8; nt++) s += res[nt][r];
    s += __shfl_xor(s, 1, 64); s += __shfl_xor(s, 2, 64);
    s += __shfl_xor(s, 4, 64); s += __shfl_xor(s, 8, 64);
    float mean = s * 0.0078125f;
    float v = 0.f;
    #pragma unroll
    for (int nt = 0; nt < 8; nt++){ float d = res[nt][r] - mean; v += d * d; }
    v += __shfl_xor(v, 1, 64); v += __shfl_xor(v, 2, 64);
    v += __shfl_xor(v, 4, 64); v += __shfl_xor(v, 8, 64);
    float rs = rsqrtf(v * 0.0078125f + 1e-5f);
    #pragma unroll
    for (int nt = 0; nt < 8; nt++)
      res[nt][r] = (res[nt][r] - mean) * rs * gv[nt] + bv[nt];
  }
}

// stage the wave's residual band to ab as bf16 (wave-private rows -> no barrier)
DEV void stage_res(const float res[8][4], __bf16* ab, int mb, int quad, int lm){
  #pragma unroll
  for (int r = 0; r < 4; r++){
    int m = mb + quad*4 + r;
    #pragma unroll
    for (int nt = 0; nt < 8; nt++)
      ab[m*ASTRIDE + nt*16 + lm] = (__bf16)res[nt][r];
  }
}

// ---------------- full encoder (MFMA), one block per sequence ----------------
// Residual stream in registers (32 f32/lane, MFMA C layout).  Grid = 512
// blocks on 256 CUs caps occupancy at 2 blocks/CU, so LDS budget is 80 KB;
// hold BOTH heads' Q/K/V -> one 24-tile QKV pass and only 2 barriers/layer.
// Pool: ab 17408 + qbuf 18432 + kb 18432 + vb 18432 = 72704 B.
// launch_bounds(256,2): VGPR cap 256 (grid caps us at 2 waves/SIMD anyway)
// -> no spill (round-2 lesson: (256,4) forced 64 VGPRs + 21 MB scratch).
__global__ __launch_bounds__(256, 2) void encoder_mfma(
    EncP P0, EncP P1, const int* __restrict__ itemid, const float* __restrict__ mask)
{
  EncP P = (blockIdx.x < 256) ? P0 : P1;
  const int b = blockIdx.x & 255;
  const int t = threadIdx.x, w = t >> 6, l = t & 63;
  const int lm = l & 15, quad = l >> 4;
  const int mb = w * 16;        // this wave's M band
  const int am = mb + lm;       // A-fragment row for this lane

  __shared__ __align__(16) char pool[72704];
  __bf16* ab   = (__bf16*)pool;                    // 64 x ASTRIDE (h/O/f1 staging)
  __bf16* qbuf = (__bf16*)(pool + 17408);          // 2 x 64 x QSTRIDE  Q (-> P)
  __bf16* kb   = (__bf16*)(pool + 35840);          // 2 x 64 x QSTRIDE  K [ki][d]
  __bf16* vb   = (__bf16*)(pool + 54272);          // 2 x 64 x QSTRIDE  V [d][ki]
  float*  hfp  = (float*)pool;                     // prologue fp32 [50][PSTRIDE]
  __shared__ float maskv[64];

  if (t < 64) maskv[t] = (t < 50) ? mask[b*50 + t] : 0.f;

  // gather + pos + LN0 (wave-per-row, coalesced) -> fp32 pool
  for (int r = w; r < 50; r += 4){
    int it = itemid[b*50 + r];
    const float* er = P.emb + (size_t)it * 128;
    float v0 = er[l]      + P.pos[r*128 + l];
    float v1 = er[l + 64] + P.pos[r*128 + l + 64];
    float m = wsum(v0 + v1) * 0.0078125f;
    float d0 = v0 - m, d1 = v1 - m;
    float var = wsum(d0*d0 + d1*d1) * 0.0078125f;
    float rs = rsqrtf(var + 1e-5f);
    hfp[r*PSTRIDE + l]      = d0 * rs * P.ln0g[l] + P.ln0b[l];
    hfp[r*PSTRIDE + l + 64] = d1 * rs * P.ln0g[l + 64] + P.ln0b[l + 64];
  }
  __syncthreads();

  // pick up this lane's residual band into registers (C layout)
  float res[8][4];
  #pragma unroll
  for (int r = 0; r < 4; r++){
    int m = mb + quad*4 + r;
    #pragma unroll
    for (int nt = 0; nt < 8; nt++)
      res[nt][r] = (m < 50) ? hfp[m*PSTRIDE + nt*16 + lm] : 0.f;
  }

  for (int lay = 0; lay < 2; ++lay){
    const __bf16* wq = P.wq + lay * 49152;
    const __bf16* wo = P.wo + lay * 16384;
    const __bf16* w1 = P.w1 + lay * 65536;
    const __bf16* w2 = P.w2 + lay * 65536;
    const float* bq  = P.bqkv + lay * 384;
    const float* bo  = P.bo   + lay * 128;
    const float* g1  = P.ln1g + lay * 128;
    const float* b1n = P.ln1b + lay * 128;
    const float* b1f = P.b1   + lay * 512;
    const float* b2f = P.b2   + lay * 128;
    const float* g2  = P.ln2g + lay * 128;
    const float* b2n = P.ln2b + lay * 128;

    // layer-top barrier: lay0 -> all hfp reads done before aliased writes;
    // lay1 -> all readers of kb/vb/qbuf finished before overwrite.
    __syncthreads();

    // h -> ab (bf16, own band), A-fragments to regs
    stage_res(res, ab, mb, quad, lm);
    bf16x8 afh[4];
    #pragma unroll
    for (int kt = 0; kt < 4; kt++)
      afh[kt] = *(const bf16x8*)&ab[am*ASTRIDE + kt*32 + quad*8];

    // ---- QKV GEMM, both heads in one pass: 24 N-tiles of [64x128]@[128x384]
    #pragma unroll
    for (int nt = 0; nt < 24; nt++){
      f32x4 acc = (f32x4){0.f,0.f,0.f,0.f};
      #pragma unroll
      for (int kt = 0; kt < 4; kt++)
        acc = MFMA16(afh[kt], *(const bf16x8*)(wq + ((size_t)(nt*4 + kt)*64 + l)*8), acc);
      int n = nt*16 + lm;
      float bias = bq[n];
      int part = n >> 7, hd = (n >> 6) & 1, d = n & 63;
      __bf16* q_ = qbuf + hd*64*QSTRIDE;
      __bf16* k_ = kb   + hd*64*QSTRIDE;
      __bf16* v_ = vb   + hd*64*QSTRIDE;
      #pragma unroll
      for (int r = 0; r < 4; r++){
        int m = mb + quad*4 + r;
        float v = acc[r] + bias;
        if (part == 0)      q_[m*QSTRIDE + d] = (__bf16)v;   // own band
        else if (part == 1) k_[m*QSTRIDE + d] = (__bf16)v;
        else                v_[d*QSTRIDE + m] = (__bf16)v;   // transposed
      }
    }
    __syncthreads();   // K/V visible to all waves

    // ---- attention, both heads, zero barriers (all wave-private) ----
    #pragma unroll
    for (int hd = 0; hd < 2; hd++){
      __bf16* q_ = qbuf + hd*64*QSTRIDE;   // Q, then P over dead Q
      const __bf16* k_ = kb + hd*64*QSTRIDE;
      const __bf16* v_ = vb + hd*64*QSTRIDE;
      bf16x8 aq0 = *(const bf16x8*)&q_[am*QSTRIDE + quad*8];
      bf16x8 aq1 = *(const bf16x8*)&q_[am*QSTRIDE + 32 + quad*8];
      f32x4 sf[4];
      #pragma unroll
      for (int nt = 0; nt < 4; nt++){
        f32x4 acc = (f32x4){0.f,0.f,0.f,0.f};
        acc = MFMA16(aq0, *(const bf16x8*)&k_[(nt*16 + lm)*QSTRIDE + quad*8], acc);
        acc = MFMA16(aq1, *(const bf16x8*)&k_[(nt*16 + lm)*QSTRIDE + 32 + quad*8], acc);
        sf[nt] = acc;
      }
      #pragma unroll
      for (int r = 0; r < 4; r++){
        int q = mb + quad*4 + r;
        float sv[4];
        float mx = -3e38f;
        #pragma unroll
        for (int nt = 0; nt < 4; nt++){
          int ki = nt*16 + lm;
          float s = sf[nt][r] * 0.125f;
          bool keep = (ki <= q) && (maskv[ki] != 0.f);
          s = keep ? s : -1e9f;
          sv[nt] = s; mx = fmaxf(mx, s);
        }
        #pragma unroll
        for (int o = 1; o < 16; o <<= 1) mx = fmaxf(mx, __shfl_xor(mx, o, 64));
        float sum = 0.f;
        #pragma unroll
        for (int nt = 0; nt < 4; nt++){ float p = __expf(sv[nt] - mx); sv[nt] = p; sum += p; }
        #pragma unroll
        for (int o = 1; o < 16; o <<= 1) sum += __shfl_xor(sum, o, 64);
        float inv = 1.f / sum;
        #pragma unroll
        for (int nt = 0; nt < 4; nt++)
          q_[q*QSTRIDE + nt*16 + lm] = (__bf16)(sv[nt] * inv);  // P over dead Q
      }
      // PV -> O into ab cols [hd*64, hd*64+64) (own band)
      bf16x8 ap0 = *(const bf16x8*)&q_[am*QSTRIDE + quad*8];
      bf16x8 ap1 = *(const bf16x8*)&q_[am*QSTRIDE + 32 + quad*8];
      #pragma unroll
      for (int nt = 0; nt < 4; nt++){
        f32x4 acc = (f32x4){0.f,0.f,0.f,0.f};
        acc = MFMA16(ap0, *(const bf16x8*)&v_[(nt*16 + lm)*QSTRIDE + quad*8], acc);
        acc = MFMA16(ap1, *(const bf16x8*)&v_[(nt*16 + lm)*QSTRIDE + 32 + quad*8], acc);
        int dcol = hd*64 + nt*16 + lm;
        #pragma unroll
        for (int r = 0; r < 4; r++)
          ab[(mb + quad*4 + r)*ASTRIDE + dcol] = (__bf16)acc[r];
      }
    }

    // ---- res += O @ Wo + bo (C layouts match) ----
    {
      bf16x8 af[4];
      #pragma unroll
      for (int kt = 0; kt < 4; kt++)
        af[kt] = *(const bf16x8*)&ab[am*ASTRIDE + kt*32 + quad*8];
      #pragma unroll
      for (int nt = 0; nt < 8; nt++){
        f32x4 acc = (f32x4){0.f,0.f,0.f,0.f};
        #pragma unroll
        for (int kt = 0; kt < 4; kt++)
          acc = MFMA16(af[kt], *(const bf16x8*)(wo + ((size_t)(nt*4 + kt)*64 + l)*8), acc);
        float bias = bo[nt*16 + lm];
        #pragma unroll
        for (int r = 0; r < 4; r++)
          res[nt][r] += acc[r] + bias;
      }
    }
    ln_reg(res, g1, b1n, lm);

    // ---- FFN fused over FF chunks of 128 (ab staging, wave-private) ----
    stage_res(res, ab, mb, quad, lm);
    {
      bf16x8 ah[4];
      #pragma unroll
      for (int kt = 0; kt < 4; kt++)
        ah[kt] = *(const bf16x8*)&ab[am*ASTRIDE + kt*32 + quad*8];
      f32x4 acc2[8];
      #pragma unroll
      for (int nt = 0; nt < 8; nt++) acc2[nt] = (f32x4){0.f,0.f,0.f,0.f};
      for (int ch = 0; ch < 4; ch++){
        #pragma unroll
        for (int nt = 0; nt < 8; nt++){
          f32x4 acc = (f32x4){0.f,0.f,0.f,0.f};
          #pragma unroll
          for (int kt = 0; kt < 4; kt++)
            acc = MFMA16(ah[kt], *(const bf16x8*)(w1 + ((size_t)((ch*8 + nt)*4 + kt)*64 + l)*8), acc);
          float bias = b1f[ch*128 + nt*16 + lm];
          #pragma unroll
          for (int r = 0; r < 4; r++)
            ab[(mb + quad*4 + r)*ASTRIDE + nt*16 + lm] = (__bf16)gelu_f(acc[r] + bias);
        }
        bf16x8 a2[4];
        #pragma unroll
        for (int kt = 0; kt < 4; kt++)
          a2[kt] = *(const bf16x8*)&ab[am*ASTRIDE + kt*32 + quad*8];
        #pragma unroll
        for (int nt = 0; nt < 8; nt++)
          #pragma unroll
          for (int kt = 0; kt < 4; kt++)
            acc2[nt] = MFMA16(a2[kt], *(const bf16x8*)(w2 + ((size_t)(nt*16 + ch*4 + kt)*64 + l)*8), acc2[nt]);
      }
      #pragma unroll
      for (int nt = 0; nt < 8; nt++){
        float bias = b2f[nt*16 + lm];
        #pragma unroll
        for (int r = 0; r < 4; r++)
          res[nt][r] += acc2[nt][r] + bias;
      }
    }
    ln_reg(res, g2, b2n, lm);
  }

  // last valid token -> transposed session emb [128][256], straight from regs
  {
    float sm = 0.f;
    for (int i = 0; i < 50; i++) sm += maskv[i];
    int idx = min(49, max(0, (int)sm - 1));
    #pragma unroll
    for (int r = 0; r < 4; r++){
      if (mb + quad*4 + r == idx){
        #pragma unroll
        for (int nt = 0; nt < 8; nt++)
          P.outT[(nt*16 + lm)*256 + b] = res[nt][r];
      }
    }
  }
}

// ---------------- scores via MFMA: 64 sessions x 128 items per block --------
// grid = 4 session-groups x 391 item-chunks.  A (sessions) staged in LDS
// bf16; B (items) streamed from pre-converted fragment-major global arrays.
// C staged through LDS for float4-coalesced writes; s1 held in regs so
// sc = 0.5*(s1 + 10*s2) needs no global re-read.
__global__ __launch_bounds__(256, 2) void scores_mfma(
    const float* __restrict__ seT, const float* __restrict__ sfT,
    const __bf16* __restrict__ ieF, const __bf16* __restrict__ xmF,
    float* __restrict__ sc, float* __restrict__ s1, float* __restrict__ s2)
{
  __shared__ __bf16 Ase[64 * ASTRIDE];
  __shared__ __bf16 Asf[64 * ASTRIDE];
  __shared__ float  Cst[64 * CSTRIDE];
  const int t = threadIdx.x, w = t >> 6, l = t & 63;
  const int lm = l & 15, quad = l >> 4;
  const int ic = blockIdx.x % 391;          // item chunk (128 items)
  const int sg = blockIdx.x / 391;          // session group (64 sessions)
  const int s0 = sg * 64;
  const size_t j0 = (size_t)ic * 128;
  const int ncols = (ic < 390) ? 128 : 80;  // 50000 = 390*128 + 80
  const int ntmax = (ncols + 15) >> 4;

  // stage A: [64 sess][128 k] bf16 from seT/sfT (fp32 [k][256])
  for (int i = t; i < 64 * 128; i += 256){
    int k = i >> 6, s = i & 63;
    Ase[s*ASTRIDE + k] = (__bf16)seT[k*256 + s0 + s];
    Asf[s*ASTRIDE + k] = (__bf16)sfT[k*256 + s0 + s];
  }
  __syncthreads();

  bf16x8 a1f[4], a2f[4];
  #pragma unroll
  for (int kt = 0; kt < 4; kt++){
    a1f[kt] = *(const bf16x8*)&Ase[(w*16 + lm)*ASTRIDE + kt*32 + quad*8];
    a2f[kt] = *(const bf16x8*)&Asf[(w*16 + lm)*ASTRIDE + kt*32 + quad*8];
  }
  f32x4 acc1[8], acc2[8];
  #pragma unroll
  for (int nt = 0; nt < 8; nt++){
    acc1[nt] = (f32x4){0.f,0.f,0.f,0.f};
    acc2[nt] = (f32x4){0.f,0.f,0.f,0.f};
  }
  for (int nt = 0; nt < ntmax; nt++){
    size_t ntg = (size_t)ic*8 + nt;
    #pragma unroll
    for (int kt = 0; kt < 4; kt++){
      acc1[nt] = MFMA16(a1f[kt], *(const bf16x8*)(ieF + ((ntg*4 + kt)*64 + l)*8), acc1[nt]);
      acc2[nt] = MFMA16(a2f[kt], *(const bf16x8*)(xmF + ((ntg*4 + kt)*64 + l)*8), acc2[nt]);
    }
  }

  // ---- s1 through LDS (float4 coalesced), held in regs for sc ----
  #pragma unroll
  for (int nt = 0; nt < 8; nt++){
    if (nt < ntmax){
      #pragma unroll
      for (int r = 0; r < 4; r++)
        Cst[(w*16 + quad*4 + r)*CSTRIDE + nt*16 + lm] = acc1[nt][r];
    }
  }
  __syncthreads();
  float4 r1[8];
  #pragma unroll
  for (int i = 0; i < 8; i++){
    int idx = i*256 + t;
    int row = idx >> 5, c4 = idx & 31;
    r1[i] = *(const float4*)&Cst[row*CSTRIDE + c4*4];
    if (c4*4 < ncols)
      *(float4*)&s1[(size_t)(s0 + row)*50000 + j0 + c4*4] = r1[i];
  }
  __syncthreads();   // all r1 reads done before Cst overwrite

  // ---- s2 + sc ----
  #pragma unroll
  for (int nt = 0; nt < 8; nt++){
    if (nt < ntmax){
      #pragma unroll
      for (int r = 0; r < 4; r++)
        Cst[(w*16 + quad*4 + r)*CSTRIDE + nt*16 + lm] = acc2[nt][r];
    }
  }
  __syncthreads();
  #pragma unroll
  for (int i = 0; i < 8; i++){
    int idx = i*256 + t;
    int row = idx >> 5, c4 = idx & 31;
    if (c4*4 < ncols){
      float4 v2 = *(const float4*)&Cst[row*CSTRIDE + c4*4];
      v2.x *= 10.f; v2.y *= 10.f; v2.z *= 10.f; v2.w *= 10.f;
      float4 vs = make_float4(0.5f*(r1[i].x + v2.x), 0.5f*(r1[i].y + v2.y),
                              0.5f*(r1[i].z + v2.z), 0.5f*(r1[i].w + v2.w));
      size_t base = (size_t)(s0 + row)*50000 + j0 + c4*4;
      *(float4*)&s2[base] = v2;
      *(float4*)&sc[base] = vs;
    }
  }
}

// ---------------- launcher ----------------
extern "C" void kernel_launch(void* const* d_in, const int* in_sizes, int n_in,
                              void* d_out, int out_size, void* d_ws, size_t ws_size,
                              hipStream_t stream)
{
  const float* x       = (const float*)d_in[0];
  const int*   itemid  = (const int*)d_in[4];
  const float* mask    = (const float*)d_in[5];
  const float* id_emb  = (const float*)d_in[6];
  const float* id_g    = (const float*)d_in[7];
  const float* id_b    = (const float*)d_in[8];
  const float* text_W  = (const float*)d_in[9];
  const float* text_b  = (const float*)d_in[10];
  const float* text_g  = (const float*)d_in[11];
  const float* text_bb = (const float*)d_in[12];

  float* out = (float*)d_out;
  float* o_scores = out;                      // [256][50000]
  float* o_s1     = out + 12800000;
  float* o_s2     = out + 25600000;
  float* o_item   = out + 38400000;           // [50000][128]
  float* o_gnn    = out + 44800000;
  float* o_xmap   = out + 51200000;

  float* seT = (float*)d_ws;                  // [128][256]
  float* sfT = seT + 32768;
  __bf16* wp   = (__bf16*)((char*)d_ws + 262144);
  __bf16* wqkv = wp;                          // 4 mats x 49152
  __bf16* wo   = wp + 196608;                 // 4 x 16384
  __bf16* w1p  = wp + 262144;                 // 4 x 65536
  __bf16* w2p  = wp + 524288;                 // 4 x 65536
  __bf16* wtx  = wp + 786432;                 // 98304 (ends at byte 2031616)
  __bf16* ieF  = (__bf16*)((char*)d_ws + 2097152);   // 12.8 MB frag-major items
  __bf16* xmF  = (__bf16*)((char*)d_ws + 14897152);  // 12.8 MB frag-major xmap

  // weight prep (bf16, fragment-major); mat order = [enc][layer]
  prep_w<<<96, 256, 0, stream>>>((const float*)d_in[16], (const float*)d_in[31], wqkv, 128, 384, 4);
  prep_w<<<32, 256, 0, stream>>>((const float*)d_in[18], (const float*)d_in[33], wo,   128, 128, 4);
  prep_w<<<128,256, 0, stream>>>((const float*)d_in[22], (const float*)d_in[37], w1p,  128, 512, 4);
  prep_w<<<128,256, 0, stream>>>((const float*)d_in[24], (const float*)d_in[39], w2p,  512, 128, 4);
  prep_w<<<48, 256, 0, stream>>>(text_W, text_W, wtx, 768, 128, 1);

  ln_kernel<<<12500, 256, 0, stream>>>(id_emb, o_item, o_gnn, id_g, id_b, 50000);
  prep_items<<<3125, 256, 0, stream>>>(o_item, ieF);
  xmap_mfma<<<782, 256, 0, stream>>>(x, wtx, text_b, o_xmap);
  ln_kernel<<<12500, 256, 0, stream>>>(o_xmap, o_xmap, nullptr, text_g, text_bb, 50000);
  prep_items<<<3125, 256, 0, stream>>>(o_xmap, xmF);

  EncP P0, P1;
  P0.pos = (const float*)d_in[13]; P0.ln0g = (const float*)d_in[14]; P0.ln0b = (const float*)d_in[15];
  P0.bqkv = (const float*)d_in[17]; P0.bo = (const float*)d_in[19];
  P0.ln1g = (const float*)d_in[20]; P0.ln1b = (const float*)d_in[21];
  P0.b1 = (const float*)d_in[23]; P0.b2 = (const float*)d_in[25];
  P0.ln2g = (const float*)d_in[26]; P0.ln2b = (const float*)d_in[27];
  P0.wq = wqkv; P0.wo = wo; P0.w1 = w1p; P0.w2 = w2p;
  P0.emb = o_item; P0.outT = seT;

  P1.pos = (const float*)d_in[28]; P1.ln0g = (const float*)d_in[29]; P1.ln0b = (const float*)d_in[30];
  P1.bqkv = (const float*)d_in[32]; P1.bo = (const float*)d_in[34];
  P1.ln1g = (const float*)d_in[35]; P1.ln1b = (const float*)d_in[36];
  P1.b1 = (const float*)d_in[38]; P1.b2 = (const float*)d_in[40];
  P1.ln2g = (const float*)d_in[41]; P1.ln2b = (const float*)d_in[42];
  P1.wq = wqkv + 2*49152; P1.wo = wo + 2*16384; P1.w1 = w1p + 2*65536; P1.w2 = w2p + 2*65536;
  P1.emb = o_xmap; P1.outT = sfT;

  encoder_mfma<<<512, 256, 0, stream>>>(P0, P1, itemid, mask);

  scores_mfma<<<1564, 256, 0, stream>>>(seT, sfT, ieF, xmF,
                                        o_scores, o_s1, o_s2);
}